// Round 1
// baseline (1094.507 us; speedup 1.0000x reference)
//
#include <hip/hip_runtime.h>
#include <stdint.h>

#define ALPHA 1.702f
#define LIMIT 7.0f

constexpr int T_TOK = 512;
constexpr int HDIM  = 2880;
constexpr int IDIM  = 2880;
constexpr int NEXP  = 8;
constexpr int GUDIM = 2 * IDIM;   // 5760
constexpr int CAP   = 512;        // per-expert row capacity (worst case)
constexpr int KDIM  = 2880;       // contraction dim for both GEMMs

constexpr int BM = 256;
constexpr int BN = 64;
constexpr int BK = 32;

typedef __attribute__((ext_vector_type(8))) short s16x8;
typedef __attribute__((ext_vector_type(4))) float f32x4;

__device__ __forceinline__ uint32_t pack2_bf16(float a, float b) {
  union { float f; uint32_t u; } x, y;
  x.f = a; y.f = b;
  uint32_t ra = (x.u + 0x7FFFu + ((x.u >> 16) & 1u)) >> 16;
  uint32_t rb = (y.u + 0x7FFFu + ((y.u >> 16) & 1u)) >> 16;
  return ra | (rb << 16);
}

__device__ __forceinline__ uint16_t f2bf(float f) {
  union { float f; uint32_t u; } x; x.f = f;
  return (uint16_t)((x.u + 0x7FFFu + ((x.u >> 16) & 1u)) >> 16);
}

// async global->LDS, 16B per lane; LDS dest = uniform base + lane*16
__device__ __forceinline__ void async_copy16(const void* g, void* l) {
  typedef __attribute__((address_space(1))) const uint32_t* gp_t;
  typedef __attribute__((address_space(3))) uint32_t* lp_t;
  __builtin_amdgcn_global_load_lds((gp_t)g, (lp_t)l, 16, 0, 0);
}

// ---------------- routing: build per-expert token lists ----------------
__global__ void routing_kernel(const int* __restrict__ ridx,
                               const float* __restrict__ rw,
                               int* __restrict__ mcount,
                               int* __restrict__ tok,
                               float* __restrict__ comb) {
  __shared__ int cnt[NEXP];
  const int t = threadIdx.x;
  if (t < NEXP) cnt[t] = 0;
  __syncthreads();
  if (t < T_TOK) {
    const int i0 = ridx[t * 4 + 0], i1 = ridx[t * 4 + 1];
    const int i2 = ridx[t * 4 + 2], i3 = ridx[t * 4 + 3];
#pragma unroll
    for (int e = 0; e < NEXP; ++e) {
      int c = (i0 == e) + (i1 == e) + (i2 == e) + (i3 == e);
      if (c) {
        int p = atomicAdd(&cnt[e], 1);
        tok[e * CAP + p]  = t;
        comb[e * CAP + p] = rw[t * NEXP + e] * (float)c;
      }
    }
  }
  __syncthreads();
  if (t < NEXP) mcount[t] = cnt[t];
}

// ---------------- gather: x rows -> packed bf16 per expert ----------------
__global__ void gather_kernel(const float* __restrict__ x,
                              const int* __restrict__ mcount,
                              const int* __restrict__ tok,
                              uint32_t* __restrict__ Apack) {
  const int m = blockIdx.x;
  const int e = blockIdx.y;
  if (m >= mcount[e]) return;
  const int t = tok[e * CAP + m];
  const float* src = x + (size_t)t * HDIM;
  uint32_t* dst = Apack + (size_t)(e * CAP + m) * (HDIM / 2);
  for (int c = threadIdx.x * 4; c < HDIM; c += 1024) {
    float4 v = *(const float4*)(src + c);
    uint2 p = make_uint2(pack2_bf16(v.x, v.y), pack2_bf16(v.z, v.w));
    *(uint2*)(dst + c / 2) = p;
  }
}

// ---------------- fused expert GEMM (gate_up+act | down+combine) ----------------
template <bool IS_GATEUP, int NDIM>
__global__ __launch_bounds__(512) void moe_gemm(
    const uint16_t* __restrict__ A,      // [NEXP][CAP][KDIM] bf16
    const float* __restrict__ W,         // [NEXP][KDIM][NDIM] fp32
    const float* __restrict__ bias,      // [NEXP][NDIM]
    const int* __restrict__ mcount,
    const int* __restrict__ tok,
    const float* __restrict__ comb,
    uint16_t* __restrict__ Hout,         // gate_up: [NEXP][CAP][IDIM]
    float* __restrict__ yout)            // down: [T][HDIM]
{
  const int e = blockIdx.z;
  const int M = mcount[e];
  const int m_base = blockIdx.y * BM;
  if (m_base >= M) return;
  const int n_base = blockIdx.x * BN;

  __shared__ uint16_t lA[BM * BK];   // [m][k], row stride 32 (64B)
  __shared__ uint16_t lB[BN * BK];   // [n][k], row stride 32 (64B)

  const int tid  = threadIdx.x;
  const int wid  = tid >> 6;
  const int lane = tid & 63;
  const int wm = wid >> 1;   // 0..3  (64 rows each)
  const int wn = wid & 1;    // 0..1  (32 cols each)

  f32x4 acc[4][2];
#pragma unroll
  for (int i = 0; i < 4; ++i)
#pragma unroll
    for (int j = 0; j < 2; ++j)
      acc[i][j] = f32x4{0.f, 0.f, 0.f, 0.f};

  // A staging: wave wid covers rows [wid*32, wid*32+32), two 16-row instrs
  const uint16_t* aP = A + ((size_t)e * CAP + m_base + wid * 32 + (lane >> 2)) * KDIM
                         + (lane & 3) * 8;
  uint16_t* lA0 = &lA[(wid * 32) * BK];
  uint16_t* lA1 = &lA[(wid * 32 + 16) * BK];

  // B staging: thread -> (n = tid&63, k quad = tid>>6), 4 fp32 loads stride NDIM
  const int bn  = tid & 63;
  const int bkq = tid >> 6;
  const float* wP = W + (size_t)e * KDIM * NDIM + (size_t)(bkq * 4) * NDIM + n_base + bn;
  uint32_t* lBw = (uint32_t*)&lB[bn * BK + bkq * 4];

  const int aRd0 = (wm * 64 + (lane & 15)) * BK + (lane >> 4) * 8;
  const int bRd0 = (wn * 32 + (lane & 15)) * BK + (lane >> 4) * 8;

  for (int kk = 0; kk < KDIM / BK; ++kk) {
    __syncthreads();
    async_copy16(aP, lA0);
    async_copy16(aP + 16 * KDIM, lA1);
    float v0 = wP[0];
    float v1 = wP[(size_t)NDIM];
    float v2 = wP[(size_t)2 * NDIM];
    float v3 = wP[(size_t)3 * NDIM];
    uint32_t p0 = pack2_bf16(v0, v1);
    uint32_t p1 = pack2_bf16(v2, v3);
    lBw[0] = p0;
    lBw[1] = p1;
    aP += BK;
    wP += (size_t)BK * NDIM;
    __syncthreads();

    s16x8 af[4], bfr[2];
#pragma unroll
    for (int mt = 0; mt < 4; ++mt)
      af[mt] = *(const s16x8*)&lA[aRd0 + mt * 16 * BK];
#pragma unroll
    for (int nt = 0; nt < 2; ++nt)
      bfr[nt] = *(const s16x8*)&lB[bRd0 + nt * 16 * BK];
#pragma unroll
    for (int mt = 0; mt < 4; ++mt)
#pragma unroll
      for (int nt = 0; nt < 2; ++nt)
        acc[mt][nt] = __builtin_amdgcn_mfma_f32_16x16x32_bf16(
            af[mt], bfr[nt], acc[mt][nt], 0, 0, 0);
  }

  // ---------------- epilogue ----------------
  const int col0 = n_base + wn * 32 + (lane & 15);   // C layout: col = lane&15
  const float b0 = bias[e * NDIM + col0];
  const float b1 = bias[e * NDIM + col0 + 16];

  if (IS_GATEUP) {
    // even col = gate, odd col = up; pair via shfl_xor(1) (adjacent lanes)
#pragma unroll
    for (int mt = 0; mt < 4; ++mt) {
      const int rbase = m_base + wm * 64 + mt * 16 + ((lane >> 4) << 2);
#pragma unroll
      for (int r = 0; r < 4; ++r) {
        float v0 = acc[mt][0][r] + b0;
        float v1 = acc[mt][1][r] + b1;
        float o0 = __shfl_xor(v0, 1, 64);
        float o1 = __shfl_xor(v1, 1, 64);
        int rr = rbase + r;
        if (rr < M && (lane & 1) == 0) {
          float g0 = fminf(v0, LIMIT);
          float u0 = fminf(fmaxf(o0, -LIMIT), LIMIT);
          float h0 = (u0 + 1.f) * (g0 / (1.f + __expf(-ALPHA * g0)));
          float g1 = fminf(v1, LIMIT);
          float u1 = fminf(fmaxf(o1, -LIMIT), LIMIT);
          float h1 = (u1 + 1.f) * (g1 / (1.f + __expf(-ALPHA * g1)));
          uint16_t* dst = Hout + ((size_t)e * CAP + rr) * IDIM;
          dst[col0 >> 1]        = f2bf(h0);
          dst[(col0 + 16) >> 1] = f2bf(h1);
        }
      }
    }
  } else {
#pragma unroll
    for (int mt = 0; mt < 4; ++mt) {
      const int rbase = m_base + wm * 64 + mt * 16 + ((lane >> 4) << 2);
#pragma unroll
      for (int r = 0; r < 4; ++r) {
        int rr = rbase + r;
        if (rr < M) {
          int t = tok[e * CAP + rr];
          float cw = comb[e * CAP + rr];
          float* yp = yout + (size_t)t * HDIM;
          atomicAdd(yp + col0,      cw * (acc[mt][0][r] + b0));
          atomicAdd(yp + col0 + 16, cw * (acc[mt][1][r] + b1));
        }
      }
    }
  }
}

extern "C" void kernel_launch(void* const* d_in, const int* in_sizes, int n_in,
                              void* d_out, int out_size, void* d_ws, size_t ws_size,
                              hipStream_t stream) {
  const float* x    = (const float*)d_in[0];
  const int*   ridx = (const int*)d_in[1];
  const float* rw   = (const float*)d_in[2];
  const float* w_gu = (const float*)d_in[3];
  const float* b_gu = (const float*)d_in[4];
  const float* w_dn = (const float*)d_in[5];
  const float* b_dn = (const float*)d_in[6];
  float* y = (float*)d_out;

  char* ws = (char*)d_ws;
  int*      mcount = (int*)ws;                                   // 8 ints
  int*      tok    = (int*)(ws + 256);                           // 8*512 ints
  float*    comb   = (float*)(ws + 256 + NEXP * CAP * 4);        // 8*512 floats
  uint16_t* Apack  = (uint16_t*)(ws + 256 + 2 * NEXP * CAP * 4); // 8*512*2880 bf16
  uint16_t* Hbuf   = Apack + (size_t)NEXP * CAP * KDIM;          // 8*512*2880 bf16

  hipMemsetAsync(y, 0, (size_t)T_TOK * HDIM * sizeof(float), stream);
  routing_kernel<<<1, 512, 0, stream>>>(ridx, rw, mcount, tok, comb);
  gather_kernel<<<dim3(CAP, NEXP), 256, 0, stream>>>(x, mcount, tok, (uint32_t*)Apack);
  moe_gemm<true, GUDIM><<<dim3(GUDIM / BN, 2, NEXP), 512, 0, stream>>>(
      Apack, w_gu, b_gu, mcount, tok, comb, Hbuf, y);
  moe_gemm<false, HDIM><<<dim3(HDIM / BN, 2, NEXP), 512, 0, stream>>>(
      Hbuf, w_dn, b_dn, mcount, tok, comb, (uint16_t*)nullptr, y);
}